// Round 10
// baseline (77.124 us; speedup 1.0000x reference)
//
#include <hip/hip_runtime.h>
#include <hip/hip_bf16.h>
#include <math.h>

// Problem dims (fixed by reference)
constexpr int B_ = 128, T_ = 512, I_ = 1024, H_ = 2048, O_ = 512;
#define BETA 0.9f

// ws float layout: y_p[4][B*I] slabs | Z[B*H]
constexpr int SLAB = B_ * I_;          // 131072 floats per partial slab
constexpr int NSLABS = 4;
constexpr int ZOFF = NSLABS * SLAB;    // 524288
constexpr int WS_FLOATS = ZOFF + B_ * H_;

typedef __attribute__((ext_vector_type(4))) short short4v;   // 4 bf16
typedef __attribute__((ext_vector_type(8))) short short8v;   // 8 bf16 (4 VGPR)
typedef __attribute__((ext_vector_type(4))) float float4v;   // 4 f32

// ---------------------------------------------------------------------------
// Kernel 1: Z = wsum*b_in, out = T*b_out  (y slabs need no init — plain stores)
// ---------------------------------------------------------------------------
__global__ __launch_bounds__(256) void init_kernel(float* __restrict__ ws,
                                                   const float* __restrict__ b_in,
                                                   const float* __restrict__ b_out,
                                                   float* __restrict__ out, float wsum) {
    int idx = blockIdx.x * 256 + threadIdx.x;
    const int total = B_ * H_ + B_ * O_;
    if (idx >= total) return;
    if (idx < B_ * H_) {
        ws[ZOFF + idx] = wsum * b_in[idx & (H_ - 1)];   // Z bias init
    } else {
        int j = idx - B_ * H_;
        out[j] = (float)T_ * b_out[j & (O_ - 1)];       // out bias init
    }
}

// ---------------------------------------------------------------------------
// Kernel 2: y_p[tc][b][i] = sum_{t in chunk tc} w[t] * x[b,t,i]
// TCH=128 -> grid = B*4 = 512 blocks, 256 threads, thread -> float4 of I.
// NO atomics: each chunk writes its own slab (nontemporal store).
// ---------------------------------------------------------------------------
constexpr int TCH = 128;
__global__ __launch_bounds__(256) void wreduce_kernel(const float* __restrict__ x,
                                                      float* __restrict__ ws) {
    __shared__ float wl[TCH];
    const int b  = blockIdx.x >> 2;   // T/TCH = 4 chunks
    const int tc = blockIdx.x & 3;
    const int t0 = tc * TCH;
    if (threadIdx.x < TCH)            // w[t] = (1-0.9^(T-t))/0.1
        wl[threadIdx.x] = (1.f - powf(BETA, (float)(T_ - (t0 + threadIdx.x)))) * 10.f;
    __syncthreads();

    const int i = threadIdx.x * 4;
    const float* xp = x + (size_t)b * T_ * I_ + (size_t)t0 * I_ + i;
    float4v acc = {0.f, 0.f, 0.f, 0.f};
#pragma unroll 4
    for (int tb = 0; tb < TCH; tb += 8) {
        float4v v[8];
#pragma unroll
        for (int j = 0; j < 8; ++j)
            v[j] = *(const float4v*)(xp + (size_t)(tb + j) * I_);
#pragma unroll
        for (int j = 0; j < 8; ++j) {
            const float wt = wl[tb + j];
            acc.x += wt * v[j].x; acc.y += wt * v[j].y;
            acc.z += wt * v[j].z; acc.w += wt * v[j].w;
        }
    }
    __builtin_nontemporal_store(acc, (float4v*)(ws + (size_t)tc * SLAB + b * I_ + i));
}

// ---------------------------------------------------------------------------
// Kernel 3/4: C[128,N] += A[128,K] @ B[K,N], bf16 MFMA builtin, f32 atomic
// epilogue. NSLAB>1: A is NSLAB partial slabs (stride B_*KGLOB) summed on load.
// Proven body (R8/R9) — only the A-load gained the slab sum.
// ---------------------------------------------------------------------------
template <int KGLOB, int NGLOB, int KCH, int NSL>
__global__ __launch_bounds__(256) void mm128(const float* __restrict__ A,
                                             const float* __restrict__ Bm,
                                             float* __restrict__ C) {
    constexpr int BN = 64, BK = 32, PAD = 8;
    __shared__ __align__(16) __hip_bfloat16 As[128][BK + PAD];  // [row][k]
    __shared__ __align__(16) __hip_bfloat16 Bs[BN][BK + PAD];   // [n][k]

    const int n0    = blockIdx.x * BN;
    const int kbase = blockIdx.y * KCH;
    const int tid   = threadIdx.x;
    const int lane  = tid & 63;
    const int w     = tid >> 6;       // wave id 0..3 -> rows [w*32, w*32+32)
    const int lo    = lane & 15;
    const int hi    = lane >> 4;

    float4v acc[2][4];
#pragma unroll
    for (int mf = 0; mf < 2; ++mf)
#pragma unroll
        for (int nf = 0; nf < 4; ++nf) acc[mf][nf] = (float4v){0.f, 0.f, 0.f, 0.f};

    for (int k0 = kbase; k0 < kbase + KCH; k0 += BK) {
        // --- stage A tile 128x32 (sum NSL slabs): row=tid>>1, half-k=(tid&1)*16
        {
            const int row = tid >> 1;
            const int kh  = (tid & 1) * 16;
            const float* ap = A + (size_t)row * KGLOB + k0 + kh;
#pragma unroll
            for (int j = 0; j < 4; ++j) {
                float4v v = *(const float4v*)(ap + 4 * j);
                if constexpr (NSL > 1) {
#pragma unroll
                    for (int p = 1; p < NSL; ++p)
                        v += *(const float4v*)(ap + (size_t)p * B_ * KGLOB + 4 * j);
                }
                union { short4v s; __hip_bfloat16 h[4]; } u;
                u.h[0] = __float2bfloat16(v.x); u.h[1] = __float2bfloat16(v.y);
                u.h[2] = __float2bfloat16(v.z); u.h[3] = __float2bfloat16(v.w);
                *(short4v*)&As[row][kh + 4 * j] = u.s;
            }
        }
        // --- stage B tile 32x64 transposed: k=tid>>3, n-chunk=(tid&7)*8
        {
            const int k  = tid >> 3;
            const int nq = (tid & 7) * 8;
            const float* bp = Bm + (size_t)(k0 + k) * NGLOB + n0 + nq;
#pragma unroll
            for (int j = 0; j < 2; ++j) {
                float4 v = *(const float4*)(bp + 4 * j);
                Bs[nq + 4 * j + 0][k] = __float2bfloat16(v.x);
                Bs[nq + 4 * j + 1][k] = __float2bfloat16(v.y);
                Bs[nq + 4 * j + 2][k] = __float2bfloat16(v.z);
                Bs[nq + 4 * j + 3][k] = __float2bfloat16(v.w);
            }
        }
        __syncthreads();
        {
            const int kk = hi * 8;   // lane's 8-wide k-group within BK=32
            short8v a[2], bv[4];
#pragma unroll
            for (int mf = 0; mf < 2; ++mf)
                a[mf] = *(const short8v*)&As[w * 32 + mf * 16 + lo][kk];
#pragma unroll
            for (int nf = 0; nf < 4; ++nf)
                bv[nf] = *(const short8v*)&Bs[nf * 16 + lo][kk];
#pragma unroll
            for (int mf = 0; mf < 2; ++mf)
#pragma unroll
                for (int nf = 0; nf < 4; ++nf)
                    acc[mf][nf] = __builtin_amdgcn_mfma_f32_16x16x32_bf16(
                        a[mf], bv[nf], acc[mf][nf], 0, 0, 0);
        }
        __syncthreads();
    }
    // --- epilogue: split-K atomic accumulate (C pre-initialized with bias)
#pragma unroll
    for (int mf = 0; mf < 2; ++mf)
#pragma unroll
        for (int nf = 0; nf < 4; ++nf)
#pragma unroll
            for (int i = 0; i < 4; ++i) {
                const int row = w * 32 + mf * 16 + hi * 4 + i;
                const int col = n0 + nf * 16 + lo;
                atomicAdd(&C[(size_t)row * NGLOB + col], acc[mf][nf][i]);
            }
}

// ---------------------------------------------------------------------------
extern "C" void kernel_launch(void* const* d_in, const int* in_sizes, int n_in,
                              void* d_out, int out_size, void* d_ws, size_t ws_size,
                              hipStream_t stream) {
    const float* x     = (const float*)d_in[0];
    const float* W_in  = (const float*)d_in[1];
    const float* b_in  = (const float*)d_in[2];
    const float* W_out = (const float*)d_in[3];
    const float* b_out = (const float*)d_in[4];
    float* out = (float*)d_out;
    float* ws  = (float*)d_ws;

    // wsum = sum_t (1-beta^(T-t))/(1-beta), exact in double on host
    const double beta = 0.9;
    const double bT = pow(beta, (double)T_);
    const float wsum = (float)(((double)T_ - beta * (1.0 - bT) / (1.0 - beta)) / (1.0 - beta));

    const int total = B_ * H_ + B_ * O_;
    init_kernel<<<(total + 255) / 256, 256, 0, stream>>>(ws, b_in, b_out, out, wsum);

    wreduce_kernel<<<B_ * (T_ / TCH), 256, 0, stream>>>(x, ws);

    // Z = (sum of 4 y-slabs) @ W_in : K=1024, split-K 8 -> 256 blocks, 4 iters
    mm128<I_, H_, 128, NSLABS><<<dim3(H_ / 64, I_ / 128), 256, 0, stream>>>(ws, W_in, ws + ZOFF);

    // out = Z @ W_out : K=2048, split-K 32 -> 256 blocks, 2 iters
    mm128<H_, O_, 64, 1><<<dim3(O_ / 64, H_ / 64), 256, 0, stream>>>(ws + ZOFF, W_out, out);
}